// Round 3
// baseline (543.265 us; speedup 1.0000x reference)
//
#include <hip/hip_runtime.h>
#include <hip/hip_bf16.h>

// SelfAttention fused kernel for MI355X (gfx950).
// Shapes: inputs [16,128,128,256] f32; Wq/Wk [256,32]; Wv [256,256].
// 2048 blocks (one per (b,h)); 512 threads (8 waves); bf16 MFMA compute.

typedef __attribute__((ext_vector_type(8))) short bf16x8;
typedef __attribute__((ext_vector_type(4))) float f32x4;
typedef __attribute__((ext_vector_type(4))) unsigned short us4;

#define WDIM 128
#define CDIM 256

// LDS layout (bytes):
//   Xs : [128][264] ushort = 67584   @ 0       (dead after V-proj)
//   qks: [128][72]  ushort = 18432   @ 67584   (cols 0..31 = q, 32..63 = k)
//   VTs: [256][136] ushort = 69632   @ 86016   (VTs[c][wv] = V[wv][c])
//   Ps : [128][136] ushort = 34816   @ 0       (overlaps dead Xs)
#define XS_STRIDE 264
#define QKS_STRIDE 72
#define VTS_STRIDE 136
#define PS_STRIDE 136
#define QKS_OFF 67584
#define VTS_OFF 86016
#define SMEM_BYTES 155648  // fits 160 KiB LDS/CU; all strides == 4 words mod 32 -> only free 2-way bank aliasing

__device__ inline unsigned short f2bf(float x) {
    union { float f; unsigned u; } v; v.f = x;
    unsigned r = v.u + 0x7FFFu + ((v.u >> 16) & 1u);  // RNE
    return (unsigned short)(r >> 16);
}

// ws layout (ushort units): WqkT [64][256] @ 0 ; WvT [256][256] @ 16384
__global__ void prep_weights(const float* __restrict__ Wq, const float* __restrict__ Wk,
                             const float* __restrict__ Wv, unsigned short* __restrict__ ws) {
    int idx = blockIdx.x * blockDim.x + threadIdx.x;
    if (idx < 64 * 256) {
        int n = idx >> 8, k = idx & 255;
        float v = (n < 32) ? Wq[k * 32 + n] : Wk[k * 32 + (n - 32)];
        ws[idx] = f2bf(v);
    } else if (idx < 64 * 256 + 256 * 256) {
        int o = idx - 64 * 256;
        int n = o >> 8, k = o & 255;
        ws[16384 + o] = f2bf(Wv[k * 256 + n]);  // WvT[n][k] = Wv[k][n]
    }
}

__global__ __launch_bounds__(512, 2)
void attn_kernel(const float* __restrict__ Xg0, const float* __restrict__ bq,
                 const float* __restrict__ bk, const float* __restrict__ bv,
                 const unsigned short* __restrict__ wsw, float* __restrict__ out) {
    extern __shared__ char smem[];
    unsigned short* Xs  = (unsigned short*)smem;
    unsigned short* qks = (unsigned short*)(smem + QKS_OFF);
    unsigned short* VTs = (unsigned short*)(smem + VTS_OFF);
    unsigned short* Ps  = (unsigned short*)smem;

    const int bh   = blockIdx.x;
    const int tid  = threadIdx.x;
    const int wid  = tid >> 6;
    const int lane = tid & 63;
    const int lm   = lane & 15;
    const int lg   = lane >> 4;

    const float* Xg = Xg0 + (size_t)bh * (WDIM * CDIM);

    // ---- Phase 1: stage X -> Xs (bf16), coalesced float4 loads ----
#pragma unroll
    for (int i = 0; i < 16; ++i) {
        int f = (i * 512 + tid) * 4;
        int row = f >> 8, col = f & 255;
        float4 v = *(const float4*)(Xg + f);
        us4 b;
        b.x = f2bf(v.x); b.y = f2bf(v.y); b.z = f2bf(v.z); b.w = f2bf(v.w);
        *(us4*)(Xs + row * XS_STRIDE + col) = b;
    }
    __syncthreads();

    // ---- Phase 2: qk = X * [Wq|Wk] + [bq|bk]  (per-wave M-tile) ----
    {
        const unsigned short* WqkT = wsw;  // [64][256]
        f32x4 acc[4] = {};
        const int row = wid * 16 + lm;
#pragma unroll
        for (int kk = 0; kk < 8; ++kk) {
            bf16x8 a = *(const bf16x8*)(Xs + row * XS_STRIDE + kk * 32 + lg * 8);
#pragma unroll
            for (int n = 0; n < 4; ++n) {
                bf16x8 b = *(const bf16x8*)(WqkT + (n * 16 + lm) * 256 + kk * 32 + lg * 8);
                acc[n] = __builtin_amdgcn_mfma_f32_16x16x32_bf16(a, b, acc[n], 0, 0, 0);
            }
        }
#pragma unroll
        for (int n = 0; n < 4; ++n) {
            int col = n * 16 + lm;
            float bias = (col < 32) ? bq[col] : bk[col - 32];
#pragma unroll
            for (int r = 0; r < 4; ++r) {
                int rr = wid * 16 + lg * 4 + r;
                qks[rr * QKS_STRIDE + col] = f2bf(acc[n][r] + bias);
            }
        }
    }

    // ---- Phase 3: V = X * Wv, stored transposed VTs[c][wv] (per-wave N-slice) ----
    {
        const unsigned short* WvT = wsw + 16384;  // [256][256]
        const int c0 = wid * 32;
        f32x4 acc[8][2] = {};
#pragma unroll
        for (int kk = 0; kk < 8; ++kk) {
            bf16x8 b0 = *(const bf16x8*)(WvT + (c0 + lm) * 256 + kk * 32 + lg * 8);
            bf16x8 b1 = *(const bf16x8*)(WvT + (c0 + 16 + lm) * 256 + kk * 32 + lg * 8);
#pragma unroll
            for (int m = 0; m < 8; ++m) {
                bf16x8 a = *(const bf16x8*)(Xs + (m * 16 + lm) * XS_STRIDE + kk * 32 + lg * 8);
                acc[m][0] = __builtin_amdgcn_mfma_f32_16x16x32_bf16(a, b0, acc[m][0], 0, 0, 0);
                acc[m][1] = __builtin_amdgcn_mfma_f32_16x16x32_bf16(a, b1, acc[m][1], 0, 0, 0);
            }
        }
#pragma unroll
        for (int m = 0; m < 8; ++m)
#pragma unroll
            for (int n = 0; n < 2; ++n) {
                int c = c0 + n * 16 + lm;
                int wv = m * 16 + lg * 4;
                us4 b;
                b.x = f2bf(acc[m][n][0]); b.y = f2bf(acc[m][n][1]);
                b.z = f2bf(acc[m][n][2]); b.w = f2bf(acc[m][n][3]);
                *(us4*)(VTs + c * VTS_STRIDE + wv) = b;  // 8B contiguous write
            }
    }
    __syncthreads();  // qks+VTs complete; Xs dead from here

    // ---- Phase 4: scores = q k^T ; wave-parallel softmax ; P -> Ps (bf16) ----
    {
        const int m = wid;  // q-row tile
        f32x4 s[8];
        bf16x8 aq = *(const bf16x8*)(qks + (m * 16 + lm) * QKS_STRIDE + lg * 8);
#pragma unroll
        for (int n = 0; n < 8; ++n) {
            bf16x8 kb = *(const bf16x8*)(qks + (n * 16 + lm) * QKS_STRIDE + 32 + lg * 8);
            f32x4 z = {};
            s[n] = __builtin_amdgcn_mfma_f32_16x16x32_bf16(aq, kb, z, 0, 0, 0);
        }
#pragma unroll
        for (int r = 0; r < 4; ++r) {
            float mx = s[0][r];
#pragma unroll
            for (int n = 1; n < 8; ++n) mx = fmaxf(mx, s[n][r]);
#pragma unroll
            for (int off = 8; off >= 1; off >>= 1) mx = fmaxf(mx, __shfl_xor(mx, off, 64));
            float p[8];
            float sum = 0.f;
#pragma unroll
            for (int n = 0; n < 8; ++n) { p[n] = __expf(s[n][r] - mx); sum += p[n]; }
#pragma unroll
            for (int off = 8; off >= 1; off >>= 1) sum += __shfl_xor(sum, off, 64);
            float rs = 1.0f / sum;
            int rr = m * 16 + lg * 4 + r;
#pragma unroll
            for (int n = 0; n < 8; ++n)
                Ps[rr * PS_STRIDE + n * 16 + lm] = f2bf(p[n] * rs);
        }
    }
    __syncthreads();

    // ---- Phase 5: out = P * V + bv  (per-wave N-slice), fp32 epilogue ----
    {
        const int c0 = wid * 32;
        f32x4 acc[8][2] = {};
#pragma unroll
        for (int kk = 0; kk < 4; ++kk) {
            bf16x8 b0 = *(const bf16x8*)(VTs + (c0 + lm) * VTS_STRIDE + kk * 32 + lg * 8);
            bf16x8 b1 = *(const bf16x8*)(VTs + (c0 + 16 + lm) * VTS_STRIDE + kk * 32 + lg * 8);
#pragma unroll
            for (int m = 0; m < 8; ++m) {
                bf16x8 a = *(const bf16x8*)(Ps + (m * 16 + lm) * PS_STRIDE + kk * 32 + lg * 8);
                acc[m][0] = __builtin_amdgcn_mfma_f32_16x16x32_bf16(a, b0, acc[m][0], 0, 0, 0);
                acc[m][1] = __builtin_amdgcn_mfma_f32_16x16x32_bf16(a, b1, acc[m][1], 0, 0, 0);
            }
        }
        float bvv[2] = { bv[c0 + lm], bv[c0 + 16 + lm] };
        float* outg = out + (size_t)bh * (WDIM * CDIM);
#pragma unroll
        for (int m = 0; m < 8; ++m)
#pragma unroll
            for (int n = 0; n < 2; ++n) {
                int c = c0 + n * 16 + lm;
#pragma unroll
                for (int r = 0; r < 4; ++r) {
                    int rr = m * 16 + lg * 4 + r;
                    outg[rr * 256 + c] = acc[m][n][r] + bvv[n];
                }
            }
    }
}

extern "C" void kernel_launch(void* const* d_in, const int* in_sizes, int n_in,
                              void* d_out, int out_size, void* d_ws, size_t ws_size,
                              hipStream_t stream) {
    const float* X  = (const float*)d_in[0];
    const float* Wq = (const float*)d_in[1];
    const float* bq = (const float*)d_in[2];
    const float* Wk = (const float*)d_in[3];
    const float* bk = (const float*)d_in[4];
    const float* Wv = (const float*)d_in[5];
    const float* bv = (const float*)d_in[6];
    unsigned short* wsw = (unsigned short*)d_ws;  // needs 163840 B

    hipFuncSetAttribute((const void*)attn_kernel,
                        hipFuncAttributeMaxDynamicSharedMemorySize, SMEM_BYTES);

    prep_weights<<<(81920 + 255) / 256, 256, 0, stream>>>(Wq, Wk, Wv, wsw);
    attn_kernel<<<2048, 512, SMEM_BYTES, stream>>>(X, bq, bk, bv, wsw, (float*)d_out);
}